// Round 8
// baseline (392.820 us; speedup 1.0000x reference)
//
#include <hip/hip_runtime.h>

typedef __bf16 bf16x8_t __attribute__((ext_vector_type(8)));
typedef float  f32x4_t  __attribute__((ext_vector_type(4)));
typedef float  floatx4  __attribute__((ext_vector_type(4)));
typedef unsigned short ushortx4 __attribute__((ext_vector_type(4)));

__device__ __forceinline__ float bf2f(unsigned short u) {
    union { unsigned int i; float f; } c; c.i = ((unsigned int)u) << 16; return c.f;
}
__device__ __forceinline__ unsigned short f2bf(float f) {
    union { float f; unsigned int i; } c; c.f = f;
    unsigned int u = c.i;
    u += 0x7fffu + ((u >> 16) & 1u);   // RNE
    return (unsigned short)(u >> 16);
}
// 8 packed bf16 (as uint4) -> 2 float4, pure bit ops (1 VALU op/elem)
__device__ __forceinline__ void cvt8(uint4 u, floatx4& lo, floatx4& hi) {
    union { unsigned int i; float f; } c;
    c.i = u.x << 16;          lo.x = c.f;
    c.i = u.x & 0xffff0000u;  lo.y = c.f;
    c.i = u.y << 16;          lo.z = c.f;
    c.i = u.y & 0xffff0000u;  lo.w = c.f;
    c.i = u.z << 16;          hi.x = c.f;
    c.i = u.z & 0xffff0000u;  hi.y = c.f;
    c.i = u.w << 16;          hi.z = c.f;
    c.i = u.w & 0xffff0000u;  hi.w = c.f;
}

// async global->LDS, 16 B per lane; lds dest = wave-uniform base + lane*16
__device__ __forceinline__ void load_lds16(const unsigned short* g, unsigned short* l) {
    __builtin_amdgcn_global_load_lds(
        (const __attribute__((address_space(1))) unsigned int*)g,
        (__attribute__((address_space(3))) unsigned int*)l, 16, 0, 0);
}

// ---------------------------------------------------------------------------
// x (f32) -> bf16, 8 elems/thread
// ---------------------------------------------------------------------------
__global__ __launch_bounds__(256) void convert_f32_bf16(
    const float* __restrict__ x, unsigned short* __restrict__ xb)
{
    size_t i = ((size_t)blockIdx.x * 256 + threadIdx.x) * 8;
    floatx4 a = *reinterpret_cast<const floatx4*>(x + i);
    floatx4 b = *reinterpret_cast<const floatx4*>(x + i + 4);
    uint4 o;
    o.x = (unsigned int)f2bf(a.x) | ((unsigned int)f2bf(a.y) << 16);
    o.y = (unsigned int)f2bf(a.z) | ((unsigned int)f2bf(a.w) << 16);
    o.z = (unsigned int)f2bf(b.x) | ((unsigned int)f2bf(b.y) << 16);
    o.w = (unsigned int)f2bf(b.z) | ((unsigned int)f2bf(b.w) << 16);
    *reinterpret_cast<uint4*>(xb + i) = o;
}

// ---------------------------------------------------------------------------
// Weight prep: Wt[n][k] (bf16) = W[k][n] (f32). 32x32 LDS-tiled transpose.
// ---------------------------------------------------------------------------
__global__ __launch_bounds__(256) void transpose_f32_to_bf16(
    const float* __restrict__ W, unsigned short* __restrict__ Wt,
    int Kdim, int Ndim)
{
    __shared__ float tile[32][33];
    const int n0 = blockIdx.x * 32, k0 = blockIdx.y * 32;
    const int tx = threadIdx.x & 31, ty = threadIdx.x >> 5;   // ty 0..7
#pragma unroll
    for (int r = 0; r < 4; ++r) {
        int k = ty + r * 8;
        tile[k][tx] = W[(size_t)(k0 + k) * Ndim + n0 + tx];
    }
    __syncthreads();
#pragma unroll
    for (int r = 0; r < 4; ++r) {
        int n = ty + r * 8;
        Wt[(size_t)(n0 + n) * Kdim + k0 + tx] = f2bf(tile[tx][n]);
    }
}

// ---------------------------------------------------------------------------
// 256x256-tile, 8-wave (2Mx4N), v4: BK=64, dbuf2 JIT pipeline.
// (R7-verified: 111us, MfmaUtil 39.5%, 0 bank conflicts, FETCH 94MB, WRITE 98MB)
// ---------------------------------------------------------------------------
#define TBM 256
#define TBN 256
#define TBK 64

template<bool C_F32>
__global__ __launch_bounds__(512, 2) void gemm_pipe_kernel(
    const unsigned short* __restrict__ A, const unsigned short* __restrict__ Wt,
    const float* __restrict__ bias, void* __restrict__ Cp,
    int N, int K, int lda, int ldc)
{
    __shared__ __align__(16) unsigned short SMEM[65536];   // 128 KiB

    const int tid  = threadIdx.x;
    const int lane = tid & 63;
    const int wid  = tid >> 6;        // 0..7
    const int wm   = wid >> 2;        // 0..1  (M half: 128 rows)
    const int wn   = wid & 3;         // 0..3  (N quarter: 64 cols)
    const int quad = lane >> 4;       // 0..3
    const int lr   = lane & 15;       // 0..15

    // XCD-aware bijective swizzle (nwg % 8 == 0 at both call sites)
    const int gx  = gridDim.x;
    const int cpx = (gx * gridDim.y) >> 3;
    const int bid = blockIdx.y * gx + blockIdx.x;
    const int nid = (bid & 7) * cpx + (bid >> 3);
    const int m0 = (nid / gx) * TBM;
    const int n0 = (nid % gx) * TBN;

    const int s_row8 = tid >> 3;                               // 0..63
    const int c_sw   = ((tid & 7) ^ (s_row8 & 7)) * 8;         // source chunk (pre-swizzled)
    const int NT     = K >> 6;

    const unsigned short* Ag = A  + (size_t)(m0 + s_row8) * lda + c_sw;
    const unsigned short* Bg = Wt + (size_t)(n0 + s_row8) * K   + c_sw;

    // buffer layout (shorts): A0 @0, A1 @16384, B0 @32768, B1 @49152
    const int sdst = wid * 512;        // + r*4096 per 64-row round

    f32x4_t acc[8][4];
#pragma unroll
    for (int i = 0; i < 8; ++i)
#pragma unroll
        for (int j = 0; j < 4; ++j)
            acc[i][j] = (f32x4_t){0.f, 0.f, 0.f, 0.f};

    // ---- prologue: stage tile 0 into buf 0 ----
#pragma unroll
    for (int r = 0; r < 4; ++r) {
        load_lds16(Ag + (size_t)(r * 64) * lda, SMEM + r * 4096 + sdst);
        load_lds16(Bg + (size_t)(r * 64) * K,   SMEM + 32768 + r * 4096 + sdst);
    }
    asm volatile("s_waitcnt vmcnt(0)" ::: "memory");
    __builtin_amdgcn_s_barrier();

    const int xk = lr & 7;             // read-side swizzle key (= row&7)

    for (int tau = 0; tau < NT; ++tau) {
        const int doff = (tau & 1) * 16384;
        const unsigned short* pa = SMEM + doff;
        const unsigned short* pb = SMEM + 32768 + doff;

        // JIT stage tile tau+1 into the other buffer (reader finished last barrier)
        if (tau + 1 < NT) {
            const int noff = ((tau + 1) & 1) * 16384;
            unsigned short* na = SMEM + noff;
            unsigned short* nb = SMEM + 32768 + noff;
            const size_t ko = (size_t)(tau + 1) * TBK;
#pragma unroll
            for (int r = 0; r < 4; ++r) {
                load_lds16(Ag + (size_t)(r * 64) * lda + ko, na + r * 4096 + sdst);
                load_lds16(Bg + (size_t)(r * 64) * K   + ko, nb + r * 4096 + sdst);
            }
        }

        bf16x8_t av[8], bv[4];
        // ---- k-half 0: chunk = quad ----
#pragma unroll
        for (int j = 0; j < 4; ++j)
            bv[j] = *reinterpret_cast<const bf16x8_t*>(
                pb + (wn * 64 + j * 16 + lr) * 64 + ((quad ^ xk) * 8));
#pragma unroll
        for (int i = 0; i < 8; ++i)
            av[i] = *reinterpret_cast<const bf16x8_t*>(
                pa + (wm * 128 + i * 16 + lr) * 64 + ((quad ^ xk) * 8));
        __builtin_amdgcn_s_setprio(1);
#pragma unroll
        for (int i = 0; i < 8; ++i)
#pragma unroll
            for (int j = 0; j < 4; ++j)
                acc[i][j] = __builtin_amdgcn_mfma_f32_16x16x32_bf16(av[i], bv[j], acc[i][j], 0, 0, 0);
        __builtin_amdgcn_s_setprio(0);

        // ---- k-half 1: chunk = 4 + quad ----
#pragma unroll
        for (int j = 0; j < 4; ++j)
            bv[j] = *reinterpret_cast<const bf16x8_t*>(
                pb + (wn * 64 + j * 16 + lr) * 64 + (((4 + quad) ^ xk) * 8));
#pragma unroll
        for (int i = 0; i < 8; ++i)
            av[i] = *reinterpret_cast<const bf16x8_t*>(
                pa + (wm * 128 + i * 16 + lr) * 64 + (((4 + quad) ^ xk) * 8));
        __builtin_amdgcn_s_setprio(1);
#pragma unroll
        for (int i = 0; i < 8; ++i)
#pragma unroll
            for (int j = 0; j < 4; ++j)
                acc[i][j] = __builtin_amdgcn_mfma_f32_16x16x32_bf16(av[i], bv[j], acc[i][j], 0, 0, 0);
        __builtin_amdgcn_s_setprio(0);

        // tile boundary: next tile fully resident (issued one full window ago)
        asm volatile("s_waitcnt vmcnt(0)" ::: "memory");
        __builtin_amdgcn_s_barrier();
    }

    // ---- epilogue ----
    if (C_F32) {
#pragma unroll
        for (int j = 0; j < 4; ++j) {
            int col = n0 + wn * 64 + j * 16 + lr;
            float bj = bias[col];
#pragma unroll
            for (int i = 0; i < 8; ++i) {
                int rbase = m0 + wm * 128 + i * 16 + quad * 4;
#pragma unroll
                for (int r = 0; r < 4; ++r) {
                    float v = acc[i][j][r] + bj;
                    ((float*)Cp)[(size_t)(rbase + r) * ldc + col] = v;
                }
            }
        }
    } else {
        // bf16: repack through the wave's private 16KB LDS slice (ring dead
        // after final barrier), XOR-chunk swizzle, then dwordx4 stores.
        unsigned short* ep = SMEM + wid * 8192;        // [128][64] shorts
#pragma unroll
        for (int j = 0; j < 4; ++j) {
            float bj = bias[n0 + wn * 64 + j * 16 + lr];
#pragma unroll
            for (int i = 0; i < 8; ++i) {
#pragma unroll
                for (int r = 0; r < 4; ++r) {
                    int row = i * 16 + quad * 4 + r;           // 0..127
                    int col = j * 16 + lr;                     // 0..63
                    int ch  = (col >> 3) ^ (row & 7);
                    ep[row * 64 + ch * 8 + (col & 7)] = f2bf(acc[i][j][r] + bj);
                }
            }
        }
        unsigned short* Cb = (unsigned short*)Cp;
        const int cch = lane & 7;
#pragma unroll
        for (int s = 0; s < 16; ++s) {
            int row = s * 8 + (lane >> 3);                     // 0..127
            int ch  = cch ^ (row & 7);
            uint4 v = *reinterpret_cast<const uint4*>(&ep[row * 64 + ch * 8]);
            *reinterpret_cast<uint4*>(
                Cb + (size_t)(m0 + wm * 128 + row) * ldc + n0 + wn * 64 + cch * 8) = v;
        }
    }
}

// ---------------------------------------------------------------------------
// Fallback GEMM (R3/R4-proven): padded LDS, regular staging.
// ---------------------------------------------------------------------------
#define BM 128
#define BN 128
#define BK 32
#define LDT 40

template<bool A_F32, bool C_F32, bool BT>
__global__ __launch_bounds__(256) void gemm_bias_kernel(
    const void* __restrict__ Ap, const void* __restrict__ Wp,
    const float* __restrict__ bias, void* __restrict__ Cp,
    int N, int K, int lda, int ldc)
{
    __shared__ __align__(16) unsigned short As[BM * LDT];
    __shared__ __align__(16) unsigned short Bs[BN * LDT];

    const int tid  = threadIdx.x;
    const int lane = tid & 63;
    const int wid  = tid >> 6;
    const int wm   = wid >> 1;
    const int wn   = wid & 1;
    const int quad = lane >> 4;
    const int lr   = lane & 15;

    const int m0 = blockIdx.y * BM;
    const int n0 = blockIdx.x * BN;

    f32x4_t acc[4][4];
#pragma unroll
    for (int i = 0; i < 4; ++i)
#pragma unroll
        for (int j = 0; j < 4; ++j)
            acc[i][j] = (f32x4_t){0.f, 0.f, 0.f, 0.f};

    for (int k0 = 0; k0 < K; k0 += BK) {
        if (A_F32) {
            const float* A = (const float*)Ap;
#pragma unroll
            for (int it = 0; it < 4; ++it) {
                int q   = tid + it * 256;
                int row = q >> 3;
                int col = (q & 7) * 4;
                floatx4 f = *reinterpret_cast<const floatx4*>(A + (size_t)(m0 + row) * lda + k0 + col);
                ushortx4 s;
                s.x = f2bf(f.x); s.y = f2bf(f.y); s.z = f2bf(f.z); s.w = f2bf(f.w);
                *reinterpret_cast<ushortx4*>(&As[row * LDT + col]) = s;
            }
        } else {
            const unsigned short* A = (const unsigned short*)Ap;
            int a_row = tid >> 2;
            int a_col = (tid & 3) * 8;
#pragma unroll
            for (int r = 0; r < 2; ++r) {
                int row = a_row + r * 64;
                uint4 u = *reinterpret_cast<const uint4*>(A + (size_t)(m0 + row) * lda + k0 + a_col);
                *reinterpret_cast<uint4*>(&As[row * LDT + a_col]) = u;
            }
        }
        if (BT) {
            const unsigned short* Wt = (const unsigned short*)Wp;
            int b_row = tid >> 2;
            int b_col = (tid & 3) * 8;
#pragma unroll
            for (int r = 0; r < 2; ++r) {
                int n = b_row + r * 64;
                uint4 u = *reinterpret_cast<const uint4*>(Wt + (size_t)(n0 + n) * K + k0 + b_col);
                *reinterpret_cast<uint4*>(&Bs[n * LDT + b_col]) = u;
            }
        } else {
            const float* W = (const float*)Wp;
#pragma unroll
            for (int it = 0; it < 4; ++it) {
                int q  = tid + it * 256;
                int kk = q >> 5;
                int nn = (q & 31) * 4;
                floatx4 f = *reinterpret_cast<const floatx4*>(W + (size_t)(k0 + kk) * N + n0 + nn);
                Bs[(nn + 0) * LDT + kk] = f2bf(f.x);
                Bs[(nn + 1) * LDT + kk] = f2bf(f.y);
                Bs[(nn + 2) * LDT + kk] = f2bf(f.z);
                Bs[(nn + 3) * LDT + kk] = f2bf(f.w);
            }
        }
        __syncthreads();

        bf16x8_t av[4], bv[4];
#pragma unroll
        for (int i = 0; i < 4; ++i)
            av[i] = *reinterpret_cast<const bf16x8_t*>(&As[(wm * 64 + i * 16 + lr) * LDT + quad * 8]);
#pragma unroll
        for (int j = 0; j < 4; ++j)
            bv[j] = *reinterpret_cast<const bf16x8_t*>(&Bs[(wn * 64 + j * 16 + lr) * LDT + quad * 8]);

#pragma unroll
        for (int i = 0; i < 4; ++i)
#pragma unroll
            for (int j = 0; j < 4; ++j)
                acc[i][j] = __builtin_amdgcn_mfma_f32_16x16x32_bf16(av[i], bv[j], acc[i][j], 0, 0, 0);

        __syncthreads();
    }

#pragma unroll
    for (int j = 0; j < 4; ++j) {
        int col = n0 + wn * 64 + j * 16 + lr;
        float bj = bias[col];
#pragma unroll
        for (int i = 0; i < 4; ++i) {
            int rbase = m0 + wm * 64 + i * 16 + quad * 4;
#pragma unroll
            for (int r = 0; r < 4; ++r) {
                float v = acc[i][j][r] + bj;
                size_t idx = (size_t)(rbase + r) * ldc + col;
                if (C_F32) ((float*)Cp)[idx] = v;
                else       ((unsigned short*)Cp)[idx] = f2bf(v);
            }
        }
    }
}

// ---------------------------------------------------------------------------
// Neighborhood attention v5: all-register, zero-LDS, zero-barrier.
//  One thread owns one (l, h) output row: q (128B) -> f32 regs; 13 k-rows
//  read DIRECTLY from global (16 h-lanes + 15 l-neighbors share each row ->
//  L1/L2 serve ~7/8 of logical traffic; no LDS staging of cache-resident
//  data — guide Common-mistake #7). Softmax entirely in registers. Second
//  pass over v. No __syncthreads anywhere; no idle lanes; no row clamping
//  (ni in [0, L-13] keeps all 13 rows in-bounds).
//  Numerics identical to v4: bf16 operands, f32 dots, SCALE at logit,
//  same rpb indexing (rp[j] at h*25 + ni - l + 12).
// ---------------------------------------------------------------------------
#define NA_L 4096
#define NA_K 13
#define NA_H 16
#define NA_SCALE 0.125f

__global__ __launch_bounds__(256) void na1d_reg_kernel(
    unsigned short* qkv, const float* __restrict__ rpb)
{
    const int t  = blockIdx.x * 256 + threadIdx.x;   // (row, head) index
    const int h  = t & 15;
    const int gl = t >> 4;                           // global row 0..16383 (b*4096+l)
    const int l  = gl & (NA_L - 1);

    int ni = l - 6;
    if (ni < 0) ni = 0;
    if (ni > NA_L - NA_K) ni = NA_L - NA_K;
    const int pi = ni - l + 12;

    const unsigned short* qp    = qkv + (size_t)gl * 3072 + h * 64;
    const unsigned short* kbase = qkv + ((size_t)(gl - l + ni)) * 3072 + 1024 + h * 64;
    const float* rp = rpb + h * 25 + pi;

    // ---- q -> 16 f32x4 regs ----
    floatx4 q[16];
#pragma unroll
    for (int c = 0; c < 8; ++c) {
        floatx4 lo, hi;
        cvt8(*reinterpret_cast<const uint4*>(qp + c * 8), lo, hi);
        q[2 * c] = lo; q[2 * c + 1] = hi;
    }

    // ---- logits ----
    float w[NA_K];
    float mx = -1e30f;
    for (int j = 0; j < NA_K; ++j) {
        const unsigned short* kp = kbase + (size_t)j * 3072;
        floatx4 a = {0.f, 0.f, 0.f, 0.f};
#pragma unroll
        for (int c = 0; c < 8; ++c) {
            floatx4 lo, hi;
            cvt8(*reinterpret_cast<const uint4*>(kp + c * 8), lo, hi);
            a += q[2 * c] * lo;
            a += q[2 * c + 1] * hi;
        }
        float s = (a.x + a.y + a.z + a.w) * NA_SCALE + rp[j];
        w[j] = s;
        mx = fmaxf(mx, s);
    }

    // ---- softmax in registers ----
    float sum = 0.f;
#pragma unroll
    for (int j = 0; j < NA_K; ++j) {
        float e = expf(w[j] - mx);
        w[j] = e;
        sum += e;
    }
    const float inv = 1.f / sum;

    // ---- AV (q regs dead; o reuses the register budget) ----
    floatx4 o[16];
#pragma unroll
    for (int i = 0; i < 16; ++i) o[i] = (floatx4){0.f, 0.f, 0.f, 0.f};
    const unsigned short* vbase = kbase + 1024;
    for (int j = 0; j < NA_K; ++j) {
        const float wj = w[j] * inv;
        const unsigned short* vp = vbase + (size_t)j * 3072;
#pragma unroll
        for (int c = 0; c < 8; ++c) {
            floatx4 lo, hi;
            cvt8(*reinterpret_cast<const uint4*>(vp + c * 8), lo, hi);
            o[2 * c]     += wj * lo;
            o[2 * c + 1] += wj * hi;
        }
    }

    // ---- pack + store into q slot ----
    unsigned short* dst = qkv + (size_t)gl * 3072 + h * 64;
#pragma unroll
    for (int c = 0; c < 8; ++c) {
        floatx4 lo = o[2 * c], hi = o[2 * c + 1];
        uint4 p;
        p.x = (unsigned int)f2bf(lo.x) | ((unsigned int)f2bf(lo.y) << 16);
        p.y = (unsigned int)f2bf(lo.z) | ((unsigned int)f2bf(lo.w) << 16);
        p.z = (unsigned int)f2bf(hi.x) | ((unsigned int)f2bf(hi.y) << 16);
        p.w = (unsigned int)f2bf(hi.z) | ((unsigned int)f2bf(hi.w) << 16);
        *reinterpret_cast<uint4*>(dst + c * 8) = p;
    }
}

// ---------------------------------------------------------------------------
extern "C" void kernel_launch(void* const* d_in, const int* in_sizes, int n_in,
                              void* d_out, int out_size, void* d_ws, size_t ws_size,
                              hipStream_t stream)
{
    const float* x      = (const float*)d_in[0];
    const float* w_qkv  = (const float*)d_in[1];
    const float* b_qkv  = (const float*)d_in[2];
    const float* rpb    = (const float*)d_in[3];
    const float* w_proj = (const float*)d_in[4];
    const float* b_proj = (const float*)d_in[5];
    float* out = (float*)d_out;

    const int M  = 4 * 4096;   // 16384
    const int K  = 1024;
    const int N1 = 3072;
    const int N2 = 1024;

    unsigned short* qkv = (unsigned short*)d_ws;              // 96 MiB
    unsigned short* Wt1 = qkv + (size_t)M * N1;               // 6 MiB
    unsigned short* Wt2 = Wt1 + (size_t)N1 * K;               // 2 MiB
    unsigned short* xb  = Wt2 + (size_t)N2 * K;               // 32 MiB
    size_t need_mid  = ((size_t)M * N1 + (size_t)N1 * K + (size_t)N2 * K) * 2;
    size_t need_fast = need_mid + (size_t)M * K * 2;

    const int na_grid = M * NA_H / 256;                        // 1024

    if (ws_size >= need_fast) {
        convert_f32_bf16<<<dim3(M * K / (256 * 8)), 256, 0, stream>>>(x, xb);
        transpose_f32_to_bf16<<<dim3(N1 / 32, K / 32), 256, 0, stream>>>(w_qkv, Wt1, K, N1);
        transpose_f32_to_bf16<<<dim3(N2 / 32, K / 32), 256, 0, stream>>>(w_proj, Wt2, K, N2);
        gemm_pipe_kernel<false><<<dim3(N1 / TBN, M / TBM), 512, 0, stream>>>(
            xb, Wt1, b_qkv, qkv, N1, K, K, N1);
        na1d_reg_kernel<<<dim3(na_grid), 256, 0, stream>>>(qkv, rpb);
        gemm_pipe_kernel<true><<<dim3(N2 / TBN, M / TBM), 512, 0, stream>>>(
            qkv, Wt2, b_proj, out, N2, K, N1, N2);
    } else if (ws_size >= need_mid) {
        transpose_f32_to_bf16<<<dim3(N1 / 32, K / 32), 256, 0, stream>>>(w_qkv, Wt1, K, N1);
        transpose_f32_to_bf16<<<dim3(N2 / 32, K / 32), 256, 0, stream>>>(w_proj, Wt2, K, N2);
        gemm_bias_kernel<true, false, true><<<dim3(N1 / BN, M / BM), 256, 0, stream>>>(
            x, Wt1, b_qkv, qkv, N1, K, K, N1);
        na1d_reg_kernel<<<dim3(na_grid), 256, 0, stream>>>(qkv, rpb);
        gemm_bias_kernel<false, true, true><<<dim3(N2 / BN, M / BM), 256, 0, stream>>>(
            qkv, Wt2, b_proj, out, N2, K, N1, N2);
    } else {
        gemm_bias_kernel<true, false, false><<<dim3(N1 / BN, M / BM), 256, 0, stream>>>(
            x, w_qkv, b_qkv, qkv, N1, K, K, N1);
        na1d_reg_kernel<<<dim3(na_grid), 256, 0, stream>>>(qkv, rpb);
        gemm_bias_kernel<false, true, false><<<dim3(N2 / BN, M / BM), 256, 0, stream>>>(
            qkv, w_proj, b_proj, out, N2, K, N1, N2);
    }
}